// Round 7
// baseline (368.025 us; speedup 1.0000x reference)
//
#include <hip/hip_runtime.h>
#include <stdint.h>
#include <stddef.h>

// HardNegativeMiningLoss on MI355X (B=8192, D=512, K=16, TEMP=0.07, labels<2048).
// kconv(bf16 + init) -> khist -> kprefsc (prefix+scatter) -> kpos2 -> kgemm
// (bf16 MFMA, R-panel LDS-resident, double-buffered Cg with 2-phase prefetch,
// per-lane register SEMI top-16 mining) -> kfin -> kfallA/kfallB -> kout.

#define TEMPV 0.07f
#define NEGV -1e30f

typedef short v8s __attribute__((ext_vector_type(8)));
typedef float v4f __attribute__((ext_vector_type(4)));

__device__ __forceinline__ short f2bf(float f) {
  unsigned u = __float_as_uint(f);
  unsigned r = (u + 0x7fffu + ((u >> 16) & 1u)) >> 16;  // RNE
  return (short)r;
}
__device__ __forceinline__ float bf2f(short s) {
  return __uint_as_float(((unsigned)(unsigned short)s) << 16);
}

__device__ __forceinline__ void gload16(const void* g, void* l) {
  __builtin_amdgcn_global_load_lds((const __attribute__((address_space(1))) unsigned*)g,
                                   (__attribute__((address_space(3))) unsigned*)l, 16, 0, 0);
}

// ---- Batcher odd-even mergesort network for 16 elements (63 comparators) ----
struct SNet { unsigned char a[64]; unsigned char b[64]; int n; };
constexpr SNet mknet16() {
  SNet t{}; t.n = 0;
  for (int p = 1; p < 16; p <<= 1)
    for (int k = p; k >= 1; k >>= 1)
      for (int j = k % p; j + k < 16; j += 2 * k)
        for (int i = 0; i < k; ++i) {
          int x = i + j, y = i + j + k;
          if (y < 16 && (x / (2 * p)) == (y / (2 * p))) {
            t.a[t.n] = (unsigned char)x; t.b[t.n] = (unsigned char)y; ++t.n;
          }
        }
  return t;
}
constexpr SNet NET16 = mknet16();
constexpr int NETN = NET16.n;

__device__ __forceinline__ void sort16d(float (&V)[16]) {
#pragma unroll
  for (int c = 0; c < NETN; ++c) {
    const int x = NET16.a[c], y = NET16.b[c];
    float hi = fmaxf(V[x], V[y]);
    float lo = fminf(V[x], V[y]);
    V[x] = hi; V[y] = lo;
  }
}

// clean a bitonic 16-seq into descending order
__device__ __forceinline__ void clean16d(float (&V)[16]) {
#pragma unroll
  for (int s = 8; s >= 1; s >>= 1) {
#pragma unroll
    for (int i = 0; i < 16; ++i) {
      if ((i & s) == 0) {
        float hi = fmaxf(V[i], V[i + s]);
        float lo = fminf(V[i], V[i + s]);
        V[i] = hi; V[i + s] = lo;
      }
    }
  }
}

// R = top16(R ∪ M), both desc sorted; in-place
__device__ __forceinline__ void mergeld(float (&R)[16], const float (&M)[16]) {
#pragma unroll
  for (int i = 0; i < 8; ++i) {
    float a = fmaxf(M[i], R[15 - i]);
    float b = fmaxf(M[15 - i], R[i]);
    R[i] = a; R[15 - i] = b;
  }
  clean16d(R);
}

// merge my desc-16 with xor-partner lane's desc-16 (both get top-16 of union)
__device__ __forceinline__ void xmerge16(float (&M)[16], int mask) {
#pragma unroll
  for (int i = 0; i < 8; ++i) {
    float pa = __shfl_xor(M[15 - i], mask);
    float pb = __shfl_xor(M[i], mask);
    M[i] = fmaxf(M[i], pa);
    M[15 - i] = fmaxf(M[15 - i], pb);
  }
  clean16d(M);
}

// ascending top-16 insert list (serial guard path only): call when v > L[0]
__device__ __forceinline__ void ins16(float (&L)[16], float v) {
#pragma unroll
  for (int k = 0; k < 15; ++k) {
    float lo = fminf(v, L[k + 1]);
    float hi = fmaxf(v, L[k + 1]);
    L[k] = lo;
    v = hi;
  }
  L[15] = v;
}

// ---------------- small setup kernels ----------------
// bf16 convert; block 0 also zeroes the small state (consumed only by later kernels)
__global__ void kconv(const float* __restrict__ emb, short* __restrict__ emb16,
                      int* hist, int* cur, float* lsum, int* nval, int* fbcnt) {
  int i = (blockIdx.x * 256 + threadIdx.x) * 4;
  float4 v = *(const float4*)(emb + i);
  short4 s;
  s.x = f2bf(v.x); s.y = f2bf(v.y); s.z = f2bf(v.z); s.w = f2bf(v.w);
  *(short4*)(emb16 + i) = s;
  if (blockIdx.x < 8) {
    int j = blockIdx.x * 256 + threadIdx.x;
    hist[j] = 0; cur[j] = 0;
    if (j == 0) { *lsum = 0.f; *nval = 0; *fbcnt = 0; }
  }
}

__global__ void khist(const int* __restrict__ lab, int* hist) {
  int i = blockIdx.x * 256 + threadIdx.x;
  if (i < 8192) atomicAdd(&hist[lab[i]], 1);
}

// single block: prefix over 2048 label counts, then scatter all 8192 rows
__global__ __launch_bounds__(256) void kprefsc(const int* __restrict__ hist,
                                               const int* __restrict__ lab,
                                               int* __restrict__ start,
                                               int* cur, int* __restrict__ rows) {
  __shared__ int part[256];
  int t = threadIdx.x;
  int v[8], loc[8], s = 0;
#pragma unroll
  for (int k = 0; k < 8; ++k) v[k] = hist[t * 8 + k];
#pragma unroll
  for (int k = 0; k < 8; ++k) { loc[k] = s; s += v[k]; }
  part[t] = s;
  __syncthreads();
  for (int off = 1; off < 256; off <<= 1) {
    int x = (t >= off) ? part[t - off] : 0;
    __syncthreads();
    part[t] += x;
    __syncthreads();
  }
  int base = (t > 0) ? part[t - 1] : 0;
#pragma unroll
  for (int k = 0; k < 8; ++k) start[t * 8 + k] = base + loc[k];
  __syncthreads();
  for (int i = t; i < 8192; i += 256) {
    int li = lab[i];
    int p = atomicAdd(&cur[li], 1);
    rows[start[li] + p] = i;
  }
}

__global__ __launch_bounds__(256) void kpos2(const short* __restrict__ emb16,
                                             const int* __restrict__ lab,
                                             const int* __restrict__ hist,
                                             const int* __restrict__ start,
                                             const int* __restrict__ rows,
                                             float* __restrict__ pmin,
                                             float* __restrict__ pterm,
                                             int* __restrict__ valid) {
  int t = threadIdx.x;
  int wv = t >> 6, lane = t & 63;
  int i = blockIdx.x * 4 + wv;
  int li = lab[i];
  int s0 = start[li], c = hist[li];
  float ei[8];
  v8s e = *(const v8s*)(emb16 + (size_t)i * 512 + lane * 8);
#pragma unroll
  for (int k = 0; k < 8; ++k) ei[k] = bf2f(e[k]);
  float smin = 1e30f, ssum = 0.f;
  for (int k = 0; k < c; ++k) {
    int j = rows[s0 + k];
    if (j == i) continue;
    v8s f = *(const v8s*)(emb16 + (size_t)j * 512 + lane * 8);
    float s = 0.f;
#pragma unroll
    for (int q = 0; q < 8; ++q) s += ei[q] * bf2f(f[q]);
#pragma unroll
    for (int off = 32; off; off >>= 1) s += __shfl_xor(s, off);
    smin = fminf(smin, s);
    ssum += s;
  }
  if (lane == 0) {
    int pc = c - 1, nc = 8192 - c;
    pmin[i] = smin;                                   // +1e30 when no positives
    pterm[i] = ssum / (float)(pc > 0 ? pc : 1) / TEMPV;
    valid[i] = (pc > 0 && nc > 0) ? 1 : 0;
  }
}

// ---------------- main mining GEMM (2-phase prefetch) ----------------
// Grid 1024 = 128 row-blocks(BM=64) x 8 col-blocks (1024 cols; cb=bid&7 -> XCD).
// LDS 128KB, 1 block/CU: Rs [64ch][64row][8] = 64KB resident; Cg double buffer
// 2 x [8ch][256col][8] = 2x32KB (256 cols x K=64 per stage). 32 stages/block
// (4 col-tiles x 8 K-chunks). Schedule per stage k: issue STAGE(k+1) loads ->
// compute stage k (8 ds_read + 32 MFMA/wave) -> [mine at col-tile end] ->
// __syncthreads (vmcnt(0) drain AFTER compute: stage latency hidden).
// Wave tile 64 rows x 64 cols: acc[mi][fi][r] = sim[fi*16+l15][wv*64+mi*16+l4*4+r].
__global__ __launch_bounds__(256, 1) void kgemm(const short* __restrict__ emb16,
                                                const int* __restrict__ lab,
                                                const float* __restrict__ pminA,
                                                float* __restrict__ Lsemi) {
  __shared__ __align__(16) char smem[131072];
  short (*Rs)[64][8] = (short (*)[64][8])smem;                       // 64KB
  short (*CgB[2])[256][8];
  CgB[0] = (short (*)[256][8])(smem + 65536);                        // 32KB
  CgB[1] = (short (*)[256][8])(smem + 65536 + 32768);                // 32KB
  float (*MS)[64][16] = (float (*)[64][16])(smem + 65536);           // alias 16KB

  int t = threadIdx.x;
  int bid = blockIdx.x;
  int rb = bid >> 3, cb = bid & 7;
  int rowbase = rb * 64;
  int colblock = cb * 1024;

  int wv = t >> 6, l = t & 63;
  int l15 = l & 15, l4 = l >> 4;
  int wcol = wv * 64;

  int rlab[4]; float pm[4];
#pragma unroll
  for (int fi = 0; fi < 4; ++fi) {
    int row = rowbase + fi * 16 + l15;
    rlab[fi] = lab[row];
    pm[fi] = pminA[row];
  }

  float RS[4][16];
#pragma unroll
  for (int fi = 0; fi < 4; ++fi)
#pragma unroll
    for (int k = 0; k < 16; ++k) RS[fi][k] = NEGV;

  // prologue: stage resident R panel (64KB) + first Cg stage; single drain
#pragma unroll
  for (int q = 0; q < 16; ++q) {
    int e = q * 256 + t;
    int ch = e >> 6, row = e & 63;
    gload16(emb16 + ((size_t)(rowbase + row) * 512 + ch * 8), &Rs[ch][row][0]);
  }
#pragma unroll
  for (int q = 0; q < 8; ++q) {
    gload16(emb16 + ((size_t)(colblock + t) * 512 + q * 8), &CgB[0][q][t][0]);
  }
  __syncthreads();

  v4f acc[4][4];
#pragma unroll
  for (int mi = 0; mi < 4; ++mi)
#pragma unroll
    for (int fi = 0; fi < 4; ++fi) acc[mi][fi] = (v4f)0.f;

  for (int k = 0; k < 32; ++k) {
    int ct = k >> 3, kk = k & 7;
    short (*cur)[256][8] = CgB[k & 1];
    short (*nxt)[256][8] = CgB[(k & 1) ^ 1];
    // phase 1: issue next stage's loads (hidden under this stage's compute)
    if (k + 1 < 32) {
      int nct = (k + 1) >> 3, nkk = (k + 1) & 7;
      int ncolstart = colblock + nct * 256;
#pragma unroll
      for (int q = 0; q < 8; ++q) {
        gload16(emb16 + ((size_t)(ncolstart + t) * 512 + nkk * 64 + q * 8),
                &nxt[q][t][0]);
      }
    }
    // phase 2: compute current stage (K=64 chunk kk of col-tile ct)
#pragma unroll
    for (int h = 0; h < 2; ++h) {
      v8s b[4], a[4];
#pragma unroll
      for (int fi = 0; fi < 4; ++fi)
        b[fi] = *(const v8s*)&Rs[kk * 8 + h * 4 + l4][fi * 16 + l15][0];
#pragma unroll
      for (int mi = 0; mi < 4; ++mi)
        a[mi] = *(const v8s*)&cur[h * 4 + l4][wcol + mi * 16 + l15][0];
#pragma unroll
      for (int mi = 0; mi < 4; ++mi)
#pragma unroll
        for (int fi = 0; fi < 4; ++fi)
          acc[mi][fi] = __builtin_amdgcn_mfma_f32_16x16x32_bf16(a[mi], b[fi],
                                                                acc[mi][fi], 0, 0, 0);
    }
    // col-tile boundary: mine full-K sums from acc, reset acc (also covers stage)
    if (kk == 7) {
      int colstart = colblock + ct * 256;
      int lc[4][4];
#pragma unroll
      for (int mm = 0; mm < 4; ++mm) {
        int4 q = *(const int4*)&lab[colstart + wcol + mm * 16 + l4 * 4];
        lc[mm][0] = q.x; lc[mm][1] = q.y; lc[mm][2] = q.z; lc[mm][3] = q.w;
      }
#pragma unroll
      for (int fi = 0; fi < 4; ++fi) {
        float S[16];
#pragma unroll
        for (int j = 0; j < 16; ++j) {
          const int mi = j >> 2, r = j & 3;
          float v = acc[mi][fi][r];
          bool keep = (lc[mi][r] != rlab[fi]) && (v < pm[fi]);
          S[j] = keep ? v : NEGV;
        }
        sort16d(S);
        mergeld(RS[fi], S);
      }
#pragma unroll
      for (int mi = 0; mi < 4; ++mi)
#pragma unroll
        for (int fi = 0; fi < 4; ++fi) acc[mi][fi] = (v4f)0.f;
    }
    // phase 3: drain (stage k+1 landed during compute) + barrier
    __syncthreads();
  }

  // cross-lane merge (4 l4-groups hold the same row), then cross-wave via LDS
#pragma unroll
  for (int fi = 0; fi < 4; ++fi) {
    xmerge16(RS[fi], 16);
    xmerge16(RS[fi], 32);
  }
  if (l4 == 0) {
#pragma unroll
    for (int fi = 0; fi < 4; ++fi)
#pragma unroll
      for (int k = 0; k < 16; ++k) MS[wv][fi * 16 + l15][k] = RS[fi][k];
  }
  __syncthreads();
  if (t < 64) {
    float R[16], M[16];
#pragma unroll
    for (int k = 0; k < 16; ++k) R[k] = MS[0][t][k];
#pragma unroll
    for (int w = 1; w < 4; ++w) {
#pragma unroll
      for (int k = 0; k < 16; ++k) M[k] = MS[w][t][k];
      mergeld(R, M);
    }
    size_t o = ((size_t)cb * 8192 + rowbase + t) * 16;
#pragma unroll
    for (int k = 0; k < 4; ++k)
      *(float4*)&Lsemi[o + k * 4] =
          make_float4(R[k * 4], R[k * 4 + 1], R[k * 4 + 2], R[k * 4 + 3]);
  }
}

// merge 8 col-block semi partials, masked LSE, detect fallback rows, reduce
__global__ __launch_bounds__(256) void kfin(const float* __restrict__ Lsemi,
                                            const float* __restrict__ pterm,
                                            const int* __restrict__ valid,
                                            float* lsum, int* nval,
                                            int* fbcnt, int* fbrows) {
  int i = blockIdx.x * 256 + threadIdx.x;
  float S[16], M[16];
#pragma unroll
  for (int k = 0; k < 16; ++k) S[k] = Lsemi[(size_t)i * 16 + k];
  for (int c = 1; c < 8; ++c) {
    size_t o = ((size_t)c * 8192 + i) * 16;
#pragma unroll
    for (int k = 0; k < 16; ++k) M[k] = Lsemi[o + k];
    mergeld(S, M);
  }
  int vd = valid[i];
  bool hs = S[0] > -1e29f;
  float li = 0.f;
  if (vd && !hs) {
    int idx = atomicAdd(fbcnt, 1);
    fbrows[idx] = i;          // loss added by kfallB
  } else if (vd) {
    float m = S[0] / TEMPV;
    float se = 0.f;
#pragma unroll
    for (int k = 0; k < 16; ++k)
      if (S[k] > -1e29f) se += expf(S[k] / TEMPV - m);
    li = m + logf(se) - pterm[i];
  }
#pragma unroll
  for (int off = 32; off; off >>= 1) {
    li += __shfl_xor(li, off);
    vd += __shfl_xor(vd, off);
  }
  __shared__ float rsd[4];
  __shared__ int rid[4];
  int wv = threadIdx.x >> 6;
  if ((threadIdx.x & 63) == 0) { rsd[wv] = li; rid[wv] = vd; }
  __syncthreads();
  if (threadIdx.x == 0) {
    atomicAdd(lsum, rsd[0] + rsd[1] + rsd[2] + rsd[3]);
    atomicAdd(nval, rid[0] + rid[1] + rid[2] + rid[3]);
  }
}

// Parallel fallback phase A: unit u = (f, j) -> row fbrows[f], candidates
// [j*256, j*256+256). One candidate per thread; block-top-16 via wave butterfly
// on wave 0; partial -> fbpart[f*32+j].
__global__ __launch_bounds__(256) void kfallA(const short* __restrict__ emb16,
                                              const int* __restrict__ lab,
                                              const int* __restrict__ fbcnt,
                                              const int* __restrict__ fbrows,
                                              float* __restrict__ fbpart) {
  int nfb = *fbcnt;
  if (nfb > 2048) nfb = 2048;
  int nunits = nfb * 32;
  __shared__ short remb[512];
  __shared__ float sims[256];
  int t = threadIdx.x;
  for (int u = blockIdx.x; u < nunits; u += gridDim.x) {
    int f = u >> 5, j = u & 31;
    int row = fbrows[f];
    int rl = lab[row];
    __syncthreads();  // prior iteration's reads of remb/sims complete
    if (t < 64) *(v8s*)&remb[t * 8] = *(const v8s*)(emb16 + (size_t)row * 512 + t * 8);
    __syncthreads();
    int c = j * 256 + t;
    float s = 0.f;
#pragma unroll 8
    for (int q = 0; q < 64; ++q) {
      v8s e = *(const v8s*)(emb16 + (size_t)c * 512 + q * 8);
      v8s r = *(const v8s*)&remb[q * 8];
#pragma unroll
      for (int z = 0; z < 8; ++z) s += bf2f(e[z]) * bf2f(r[z]);
    }
    sims[t] = (lab[c] != rl) ? s : NEGV;
    __syncthreads();
    if (t < 64) {
      float M[16];
#pragma unroll
      for (int k = 0; k < 16; ++k) M[k] = NEGV;
      M[0] = sims[t]; M[1] = sims[64 + t]; M[2] = sims[128 + t]; M[3] = sims[192 + t];
      sort16d(M);
      xmerge16(M, 1); xmerge16(M, 2); xmerge16(M, 4);
      xmerge16(M, 8); xmerge16(M, 16); xmerge16(M, 32);
      if (t == 0) {
#pragma unroll
        for (int k = 0; k < 16; ++k) fbpart[(size_t)(f * 32 + j) * 16 + k] = M[k];
      }
    }
  }
}

// Parallel fallback phase B: one thread per fallback row merges 32 partials,
// computes LSE, adds loss. Serial exact path only for f >= 2048 (never expected).
__global__ __launch_bounds__(256) void kfallB(const short* __restrict__ emb16,
                                              const int* __restrict__ lab,
                                              const int* __restrict__ fbcnt,
                                              const int* __restrict__ fbrows,
                                              const float* __restrict__ fbpart,
                                              const float* __restrict__ pterm,
                                              float* lsum) {
  int nfb = *fbcnt;
  int gid = blockIdx.x * 256 + threadIdx.x;
  for (int f = gid; f < nfb; f += gridDim.x * 256) {
    int row = fbrows[f];
    float R[16];
    if (f < 2048) {
#pragma unroll
      for (int k = 0; k < 16; ++k) R[k] = fbpart[(size_t)(f * 32) * 16 + k];
      for (int j = 1; j < 32; ++j) {
        float M[16];
#pragma unroll
        for (int k = 0; k < 16; ++k) M[k] = fbpart[(size_t)(f * 32 + j) * 16 + k];
        mergeld(R, M);
      }
    } else {
      // correctness guard; never expected to execute
      int rl = lab[row];
      float L[16];
#pragma unroll
      for (int k = 0; k < 16; ++k) L[k] = NEGV;
      for (int c = 0; c < 8192; ++c) {
        if (lab[c] == rl) continue;
        float s = 0.f;
        for (int q = 0; q < 64; ++q) {
          v8s e = *(const v8s*)(emb16 + (size_t)c * 512 + q * 8);
          v8s r = *(const v8s*)(emb16 + (size_t)row * 512 + q * 8);
#pragma unroll
          for (int z = 0; z < 8; ++z) s += bf2f(e[z]) * bf2f(r[z]);
        }
        if (s > L[0]) ins16(L, s);
      }
#pragma unroll
      for (int k = 0; k < 16; ++k) R[k] = L[15 - k];
    }
    float m = R[0] / TEMPV;
    float se = 0.f;
#pragma unroll
    for (int k = 0; k < 16; ++k)
      if (R[k] > -1e29f) se += expf(R[k] / TEMPV - m);
    float lse = m + logf(se);
    atomicAdd(lsum, lse - pterm[row]);
  }
}

__global__ void kout(const float* lsum, const int* nval, float* out) {
  if (threadIdx.x == 0 && blockIdx.x == 0)
    out[0] = lsum[0] / (float)(nval[0] > 0 ? nval[0] : 1);
}

extern "C" void kernel_launch(void* const* d_in, const int* in_sizes, int n_in,
                              void* d_out, int out_size, void* d_ws, size_t ws_size,
                              hipStream_t stream) {
  const float* emb = (const float*)d_in[0];
  const int* lab = (const int*)d_in[1];
  float* out = (float*)d_out;

  char* wsb = (char*)d_ws;
  short* emb16 = (short*)wsb;                       // 8,388,608
  int* hist = (int*)(wsb + 8388608);                // 8,192
  int* cur = (int*)(wsb + 8396800);                 // 8,192
  int* start = (int*)(wsb + 8404992);               // 8,192
  int* rows = (int*)(wsb + 8413184);                // 32,768
  float* pmin = (float*)(wsb + 8445952);            // 32,768
  float* pterm = (float*)(wsb + 8478720);           // 32,768
  int* valid = (int*)(wsb + 8511488);               // 32,768
  float* LsemiW = (float*)(wsb + 8544256);          // 4,194,304
  int* fbcnt = (int*)(wsb + 12738560);              // 4 (+pad 64)
  int* fbrows = (int*)(wsb + 12738624);             // 32,768
  float* fbpart = (float*)(wsb + 12771392);         // 4,194,304 (2048*32*16 f32)
  float* lsum = (float*)(wsb + 16965696);           // 4
  int* nval = (int*)(wsb + 16965700);               // 4

  kconv<<<4096, 256, 0, stream>>>(emb, emb16, hist, cur, lsum, nval, fbcnt);
  khist<<<32, 256, 0, stream>>>(lab, hist);
  kprefsc<<<1, 256, 0, stream>>>(hist, lab, start, cur, rows);
  kpos2<<<2048, 256, 0, stream>>>(emb16, lab, hist, start, rows, pmin, pterm, valid);
  kgemm<<<1024, 256, 0, stream>>>(emb16, lab, pmin, LsemiW);
  kfin<<<32, 256, 0, stream>>>(LsemiW, pterm, valid, lsum, nval, fbcnt, fbrows);
  kfallA<<<256, 256, 0, stream>>>(emb16, lab, fbcnt, fbrows, fbpart);
  kfallB<<<32, 256, 0, stream>>>(emb16, lab, fbcnt, fbrows, fbpart, pterm, lsum);
  kout<<<1, 64, 0, stream>>>(lsum, nval, out);
}

// Round 8
// 286.715 us; speedup vs baseline: 1.2836x; 1.2836x over previous
//
#include <hip/hip_runtime.h>
#include <stdint.h>
#include <stddef.h>

// HardNegativeMiningLoss on MI355X (B=8192, D=512, K=16, TEMP=0.07, labels<2048).
// kconv(bf16+init) -> khist -> kprefsc -> kpos2 -> kgemm (bf16 MFMA, T3 2-phase
// double-buffered staging with raw barriers + asm vmcnt drain AFTER compute,
// per-lane register SEMI top-16 mining) -> kfin -> kfallA/kfallB -> kout.

#define TEMPV 0.07f
#define NEGV -1e30f

typedef short v8s __attribute__((ext_vector_type(8)));
typedef float v4f __attribute__((ext_vector_type(4)));

__device__ __forceinline__ short f2bf(float f) {
  unsigned u = __float_as_uint(f);
  unsigned r = (u + 0x7fffu + ((u >> 16) & 1u)) >> 16;  // RNE
  return (short)r;
}
__device__ __forceinline__ float bf2f(short s) {
  return __uint_as_float(((unsigned)(unsigned short)s) << 16);
}

__device__ __forceinline__ void gload16(const void* g, void* l) {
  __builtin_amdgcn_global_load_lds((const __attribute__((address_space(1))) unsigned*)g,
                                   (__attribute__((address_space(3))) unsigned*)l, 16, 0, 0);
}

// ---- Batcher odd-even mergesort network for 16 elements (63 comparators) ----
struct SNet { unsigned char a[64]; unsigned char b[64]; int n; };
constexpr SNet mknet16() {
  SNet t{}; t.n = 0;
  for (int p = 1; p < 16; p <<= 1)
    for (int k = p; k >= 1; k >>= 1)
      for (int j = k % p; j + k < 16; j += 2 * k)
        for (int i = 0; i < k; ++i) {
          int x = i + j, y = i + j + k;
          if (y < 16 && (x / (2 * p)) == (y / (2 * p))) {
            t.a[t.n] = (unsigned char)x; t.b[t.n] = (unsigned char)y; ++t.n;
          }
        }
  return t;
}
constexpr SNet NET16 = mknet16();
constexpr int NETN = NET16.n;

__device__ __forceinline__ void sort16d(float (&V)[16]) {
#pragma unroll
  for (int c = 0; c < NETN; ++c) {
    const int x = NET16.a[c], y = NET16.b[c];
    float hi = fmaxf(V[x], V[y]);
    float lo = fminf(V[x], V[y]);
    V[x] = hi; V[y] = lo;
  }
}

// clean a bitonic 16-seq into descending order
__device__ __forceinline__ void clean16d(float (&V)[16]) {
#pragma unroll
  for (int s = 8; s >= 1; s >>= 1) {
#pragma unroll
    for (int i = 0; i < 16; ++i) {
      if ((i & s) == 0) {
        float hi = fmaxf(V[i], V[i + s]);
        float lo = fminf(V[i], V[i + s]);
        V[i] = hi; V[i + s] = lo;
      }
    }
  }
}

// R = top16(R ∪ M), both desc sorted; in-place
__device__ __forceinline__ void mergeld(float (&R)[16], const float (&M)[16]) {
#pragma unroll
  for (int i = 0; i < 8; ++i) {
    float a = fmaxf(M[i], R[15 - i]);
    float b = fmaxf(M[15 - i], R[i]);
    R[i] = a; R[15 - i] = b;
  }
  clean16d(R);
}

// merge my desc-16 with xor-partner lane's desc-16 (both get top-16 of union)
__device__ __forceinline__ void xmerge16(float (&M)[16], int mask) {
#pragma unroll
  for (int i = 0; i < 8; ++i) {
    float pa = __shfl_xor(M[15 - i], mask);
    float pb = __shfl_xor(M[i], mask);
    M[i] = fmaxf(M[i], pa);
    M[15 - i] = fmaxf(M[15 - i], pb);
  }
  clean16d(M);
}

// ascending top-16 insert list (serial guard path only): call when v > L[0]
__device__ __forceinline__ void ins16(float (&L)[16], float v) {
#pragma unroll
  for (int k = 0; k < 15; ++k) {
    float lo = fminf(v, L[k + 1]);
    float hi = fmaxf(v, L[k + 1]);
    L[k] = lo;
    v = hi;
  }
  L[15] = v;
}

// ---------------- small setup kernels ----------------
// bf16 convert; first 8 blocks also zero the small state
__global__ void kconv(const float* __restrict__ emb, short* __restrict__ emb16,
                      int* hist, int* cur, float* lsum, int* nval, int* fbcnt) {
  int i = (blockIdx.x * 256 + threadIdx.x) * 4;
  float4 v = *(const float4*)(emb + i);
  short4 s;
  s.x = f2bf(v.x); s.y = f2bf(v.y); s.z = f2bf(v.z); s.w = f2bf(v.w);
  *(short4*)(emb16 + i) = s;
  if (blockIdx.x < 8) {
    int j = blockIdx.x * 256 + threadIdx.x;
    hist[j] = 0; cur[j] = 0;
    if (j == 0) { *lsum = 0.f; *nval = 0; *fbcnt = 0; }
  }
}

__global__ void khist(const int* __restrict__ lab, int* hist) {
  int i = blockIdx.x * 256 + threadIdx.x;
  if (i < 8192) atomicAdd(&hist[lab[i]], 1);
}

// single block: prefix over 2048 label counts, then scatter all 8192 rows
__global__ __launch_bounds__(256) void kprefsc(const int* __restrict__ hist,
                                               const int* __restrict__ lab,
                                               int* __restrict__ start,
                                               int* cur, int* __restrict__ rows) {
  __shared__ int part[256];
  int t = threadIdx.x;
  int v[8], loc[8], s = 0;
#pragma unroll
  for (int k = 0; k < 8; ++k) v[k] = hist[t * 8 + k];
#pragma unroll
  for (int k = 0; k < 8; ++k) { loc[k] = s; s += v[k]; }
  part[t] = s;
  __syncthreads();
  for (int off = 1; off < 256; off <<= 1) {
    int x = (t >= off) ? part[t - off] : 0;
    __syncthreads();
    part[t] += x;
    __syncthreads();
  }
  int base = (t > 0) ? part[t - 1] : 0;
#pragma unroll
  for (int k = 0; k < 8; ++k) start[t * 8 + k] = base + loc[k];
  __syncthreads();
  for (int i = t; i < 8192; i += 256) {
    int li = lab[i];
    int p = atomicAdd(&cur[li], 1);
    rows[start[li] + p] = i;
  }
}

__global__ __launch_bounds__(256) void kpos2(const short* __restrict__ emb16,
                                             const int* __restrict__ lab,
                                             const int* __restrict__ hist,
                                             const int* __restrict__ start,
                                             const int* __restrict__ rows,
                                             float* __restrict__ pmin,
                                             float* __restrict__ pterm,
                                             int* __restrict__ valid) {
  int t = threadIdx.x;
  int wv = t >> 6, lane = t & 63;
  int i = blockIdx.x * 4 + wv;
  int li = lab[i];
  int s0 = start[li], c = hist[li];
  float ei[8];
  v8s e = *(const v8s*)(emb16 + (size_t)i * 512 + lane * 8);
#pragma unroll
  for (int k = 0; k < 8; ++k) ei[k] = bf2f(e[k]);
  float smin = 1e30f, ssum = 0.f;
  for (int k = 0; k < c; ++k) {
    int j = rows[s0 + k];
    if (j == i) continue;
    v8s f = *(const v8s*)(emb16 + (size_t)j * 512 + lane * 8);
    float s = 0.f;
#pragma unroll
    for (int q = 0; q < 8; ++q) s += ei[q] * bf2f(f[q]);
#pragma unroll
    for (int off = 32; off; off >>= 1) s += __shfl_xor(s, off);
    smin = fminf(smin, s);
    ssum += s;
  }
  if (lane == 0) {
    int pc = c - 1, nc = 8192 - c;
    pmin[i] = smin;                                   // +1e30 when no positives
    pterm[i] = ssum / (float)(pc > 0 ? pc : 1) / TEMPV;
    valid[i] = (pc > 0 && nc > 0) ? 1 : 0;
  }
}

// ---------------- main mining GEMM (T3 2-phase, raw barriers) ----------------
// Grid 1024 = 128 row-blocks(BM=64) x 8 col-blocks (1024 cols; cb=bid&7 -> XCD).
// LDS 80KB -> 2 blocks/CU: Rs dbuf 2x[8ch][64row][8] (8KB/buf) + Cg dbuf
// 2x[8ch][256col][8] (32KB/buf). 32 stages = 4 col-tiles(256) x 8 K-chunks(64).
// Per stage (T3 ordering, critical): (1) ALL ds_reads of current buffers ->
// (2) issue next stage's 10 global_load_lds -> (3) 32 MFMA -> (4) mine at kc==7
// -> (5) asm s_waitcnt vmcnt(0) [memory clobber] -> (6) raw s_barrier.
// Reads precede the new LDS writes in program order, so no conservative drain
// lands before them; the drain after MFMA has ~620cy of cover.
// Waves 2x2: wave tile 32 rows x 128 cols. acc[mi][fi][r] =
// sim[wr*32+fi*16+l15][ct*256 + wc*128 + mi*16 + l4*4 + r].
__global__ __launch_bounds__(256, 2) void kgemm(const short* __restrict__ emb16,
                                                const int* __restrict__ lab,
                                                const float* __restrict__ pminA,
                                                float* __restrict__ Lsemi) {
  __shared__ __align__(16) char smem[81920];
  short (*Rs)[8][64][8] = (short (*)[8][64][8])smem;              // 2 x 8KB
  short (*Cg)[8][256][8] = (short (*)[8][256][8])(smem + 16384);  // 2 x 32KB
  float (*MS)[16] = (float (*)[16])smem;                          // alias 4KB

  int t = threadIdx.x;
  int bid = blockIdx.x;
  int rb = bid >> 3, cb = bid & 7;
  int rowbase = rb * 64;
  int colblock = cb * 1024;

  int wv = t >> 6, l = t & 63;
  int l15 = l & 15, l4 = l >> 4;
  int wr = wv >> 1, wc = wv & 1;

  int rlab[2]; float pm[2];
#pragma unroll
  for (int fi = 0; fi < 2; ++fi) {
    int row = rowbase + wr * 32 + fi * 16 + l15;
    rlab[fi] = lab[row];
    pm[fi] = pminA[row];
  }

  float RS[2][16];
#pragma unroll
  for (int fi = 0; fi < 2; ++fi)
#pragma unroll
    for (int k = 0; k < 16; ++k) RS[fi][k] = NEGV;

  v4f acc[8][2];
#pragma unroll
  for (int mi = 0; mi < 8; ++mi)
#pragma unroll
    for (int fi = 0; fi < 2; ++fi) acc[mi][fi] = (v4f)0.f;

  // prologue: stage s=0 into buf 0, drain, barrier
#pragma unroll
  for (int q = 0; q < 2; ++q) {
    int e = q * 256 + t, ch = e >> 6, row = e & 63;
    gload16(emb16 + ((size_t)(rowbase + row) * 512 + ch * 8), &Rs[0][ch][row][0]);
  }
#pragma unroll
  for (int q = 0; q < 8; ++q) {
    int e = q * 256 + t, ch = e >> 8, col = e & 255;
    gload16(emb16 + ((size_t)(colblock + col) * 512 + ch * 8), &Cg[0][ch][col][0]);
  }
  asm volatile("s_waitcnt vmcnt(0)" ::: "memory");
  __builtin_amdgcn_s_barrier();

  for (int s = 0; s < 32; ++s) {
    const int ct = s >> 3, kc = s & 7;
    const int cur = s & 1;
    // (1) all ds_reads of the current stage (BEFORE any new LDS writes)
    v8s b[2][2], a[2][8];
#pragma unroll
    for (int h = 0; h < 2; ++h) {
#pragma unroll
      for (int fi = 0; fi < 2; ++fi)
        b[h][fi] = *(const v8s*)&Rs[cur][h * 4 + l4][wr * 32 + fi * 16 + l15][0];
#pragma unroll
      for (int mi = 0; mi < 8; ++mi)
        a[h][mi] = *(const v8s*)&Cg[cur][h * 4 + l4][wc * 128 + mi * 16 + l15][0];
    }
    // (2) issue next stage's loads into the other buffers
    if (s + 1 < 32) {
      const int nct = (s + 1) >> 3, nkc = (s + 1) & 7;
      const int nb = (s + 1) & 1;
#pragma unroll
      for (int q = 0; q < 2; ++q) {
        int e = q * 256 + t, ch = e >> 6, row = e & 63;
        gload16(emb16 + ((size_t)(rowbase + row) * 512 + nkc * 64 + ch * 8),
                &Rs[nb][ch][row][0]);
      }
#pragma unroll
      for (int q = 0; q < 8; ++q) {
        int e = q * 256 + t, ch = e >> 8, col = e & 255;
        gload16(emb16 + ((size_t)(colblock + nct * 256 + col) * 512 + nkc * 64 + ch * 8),
                &Cg[nb][ch][col][0]);
      }
    }
    // (3) MFMA (register-only)
#pragma unroll
    for (int h = 0; h < 2; ++h)
#pragma unroll
      for (int mi = 0; mi < 8; ++mi)
#pragma unroll
        for (int fi = 0; fi < 2; ++fi)
          acc[mi][fi] = __builtin_amdgcn_mfma_f32_16x16x32_bf16(a[h][mi], b[h][fi],
                                                                acc[mi][fi], 0, 0, 0);
    // (4) mine at col-tile end (VALU; extra cover for the in-flight stage)
    if (kc == 7) {
      const int colstart = colblock + ct * 256 + wc * 128;
#pragma unroll
      for (int c = 0; c < 2; ++c) {
        int lc[4][4];
#pragma unroll
        for (int mm = 0; mm < 4; ++mm) {
          int4 q = *(const int4*)&lab[colstart + (c * 4 + mm) * 16 + l4 * 4];
          lc[mm][0] = q.x; lc[mm][1] = q.y; lc[mm][2] = q.z; lc[mm][3] = q.w;
        }
#pragma unroll
        for (int fi = 0; fi < 2; ++fi) {
          float S[16];
#pragma unroll
          for (int j = 0; j < 16; ++j) {
            const int mi = c * 4 + (j >> 2), r = j & 3;
            float v = acc[mi][fi][r];
            bool keep = (lc[j >> 2][r] != rlab[fi]) && (v < pm[fi]);
            S[j] = keep ? v : NEGV;
          }
          sort16d(S);
          mergeld(RS[fi], S);
        }
      }
#pragma unroll
      for (int mi = 0; mi < 8; ++mi)
#pragma unroll
        for (int fi = 0; fi < 2; ++fi) acc[mi][fi] = (v4f)0.f;
    }
    // (5) drain next-stage loads (covered by MFMA+mining), (6) barrier
    asm volatile("s_waitcnt vmcnt(0)" ::: "memory");
    __builtin_amdgcn_s_barrier();
  }

  // cross-lane merge (4 l4-groups share a row), then cross-wave (wc pair) via LDS
#pragma unroll
  for (int fi = 0; fi < 2; ++fi) {
    xmerge16(RS[fi], 16);
    xmerge16(RS[fi], 32);
  }
  if (wc == 1 && l4 == 0) {
#pragma unroll
    for (int fi = 0; fi < 2; ++fi)
#pragma unroll
      for (int k = 0; k < 16; ++k) MS[wr * 32 + fi * 16 + l15][k] = RS[fi][k];
  }
  __syncthreads();
  if (wc == 0 && l4 == 0) {
#pragma unroll
    for (int fi = 0; fi < 2; ++fi) {
      int row = wr * 32 + fi * 16 + l15;
      float M[16];
#pragma unroll
      for (int k = 0; k < 16; ++k) M[k] = MS[row][k];
      mergeld(RS[fi], M);
      size_t o = ((size_t)cb * 8192 + rowbase + row) * 16;
#pragma unroll
      for (int k = 0; k < 4; ++k)
        *(float4*)&Lsemi[o + k * 4] = make_float4(RS[fi][k * 4], RS[fi][k * 4 + 1],
                                                  RS[fi][k * 4 + 2], RS[fi][k * 4 + 3]);
    }
  }
}

// merge 8 col-block semi partials, masked LSE, detect fallback rows, reduce
__global__ __launch_bounds__(256) void kfin(const float* __restrict__ Lsemi,
                                            const float* __restrict__ pterm,
                                            const int* __restrict__ valid,
                                            float* lsum, int* nval,
                                            int* fbcnt, int* fbrows) {
  int i = blockIdx.x * 256 + threadIdx.x;
  float S[16], M[16];
#pragma unroll
  for (int k = 0; k < 16; ++k) S[k] = Lsemi[(size_t)i * 16 + k];
  for (int c = 1; c < 8; ++c) {
    size_t o = ((size_t)c * 8192 + i) * 16;
#pragma unroll
    for (int k = 0; k < 16; ++k) M[k] = Lsemi[o + k];
    mergeld(S, M);
  }
  int vd = valid[i];
  bool hs = S[0] > -1e29f;
  float li = 0.f;
  if (vd && !hs) {
    int idx = atomicAdd(fbcnt, 1);
    fbrows[idx] = i;          // loss added by kfallB
  } else if (vd) {
    float m = S[0] / TEMPV;
    float se = 0.f;
#pragma unroll
    for (int k = 0; k < 16; ++k)
      if (S[k] > -1e29f) se += expf(S[k] / TEMPV - m);
    li = m + logf(se) - pterm[i];
  }
#pragma unroll
  for (int off = 32; off; off >>= 1) {
    li += __shfl_xor(li, off);
    vd += __shfl_xor(vd, off);
  }
  __shared__ float rsd[4];
  __shared__ int rid[4];
  int wv = threadIdx.x >> 6;
  if ((threadIdx.x & 63) == 0) { rsd[wv] = li; rid[wv] = vd; }
  __syncthreads();
  if (threadIdx.x == 0) {
    atomicAdd(lsum, rsd[0] + rsd[1] + rsd[2] + rsd[3]);
    atomicAdd(nval, rid[0] + rid[1] + rid[2] + rid[3]);
  }
}

// Parallel fallback phase A: unit u = (f, j) -> row fbrows[f], candidates
// [j*256, j*256+256). One candidate per thread; block-top-16 via wave butterfly
// on wave 0; partial -> fbpart[f*32+j].
__global__ __launch_bounds__(256) void kfallA(const short* __restrict__ emb16,
                                              const int* __restrict__ lab,
                                              const int* __restrict__ fbcnt,
                                              const int* __restrict__ fbrows,
                                              float* __restrict__ fbpart) {
  int nfb = *fbcnt;
  if (nfb > 2048) nfb = 2048;
  int nunits = nfb * 32;
  __shared__ short remb[512];
  __shared__ float sims[256];
  int t = threadIdx.x;
  for (int u = blockIdx.x; u < nunits; u += gridDim.x) {
    int f = u >> 5, j = u & 31;
    int row = fbrows[f];
    int rl = lab[row];
    __syncthreads();  // prior iteration's reads of remb/sims complete
    if (t < 64) *(v8s*)&remb[t * 8] = *(const v8s*)(emb16 + (size_t)row * 512 + t * 8);
    __syncthreads();
    int c = j * 256 + t;
    float s = 0.f;
#pragma unroll 8
    for (int q = 0; q < 64; ++q) {
      v8s e = *(const v8s*)(emb16 + (size_t)c * 512 + q * 8);
      v8s r = *(const v8s*)&remb[q * 8];
#pragma unroll
      for (int z = 0; z < 8; ++z) s += bf2f(e[z]) * bf2f(r[z]);
    }
    sims[t] = (lab[c] != rl) ? s : NEGV;
    __syncthreads();
    if (t < 64) {
      float M[16];
#pragma unroll
      for (int k = 0; k < 16; ++k) M[k] = NEGV;
      M[0] = sims[t]; M[1] = sims[64 + t]; M[2] = sims[128 + t]; M[3] = sims[192 + t];
      sort16d(M);
      xmerge16(M, 1); xmerge16(M, 2); xmerge16(M, 4);
      xmerge16(M, 8); xmerge16(M, 16); xmerge16(M, 32);
      if (t == 0) {
#pragma unroll
        for (int k = 0; k < 16; ++k) fbpart[(size_t)(f * 32 + j) * 16 + k] = M[k];
      }
    }
  }
}

// Parallel fallback phase B: one thread per fallback row merges 32 partials,
// computes LSE, adds loss. Serial exact path only for f >= 2048 (never expected).
__global__ __launch_bounds__(256) void kfallB(const short* __restrict__ emb16,
                                              const int* __restrict__ lab,
                                              const int* __restrict__ fbcnt,
                                              const int* __restrict__ fbrows,
                                              const float* __restrict__ fbpart,
                                              const float* __restrict__ pterm,
                                              float* lsum) {
  int nfb = *fbcnt;
  int gid = blockIdx.x * 256 + threadIdx.x;
  for (int f = gid; f < nfb; f += gridDim.x * 256) {
    int row = fbrows[f];
    float R[16];
    if (f < 2048) {
#pragma unroll
      for (int k = 0; k < 16; ++k) R[k] = fbpart[(size_t)(f * 32) * 16 + k];
      for (int j = 1; j < 32; ++j) {
        float M[16];
#pragma unroll
        for (int k = 0; k < 16; ++k) M[k] = fbpart[(size_t)(f * 32 + j) * 16 + k];
        mergeld(R, M);
      }
    } else {
      // correctness guard; never expected to execute
      int rl = lab[row];
      float L[16];
#pragma unroll
      for (int k = 0; k < 16; ++k) L[k] = NEGV;
      for (int c = 0; c < 8192; ++c) {
        if (lab[c] == rl) continue;
        float s = 0.f;
        for (int q = 0; q < 64; ++q) {
          v8s e = *(const v8s*)(emb16 + (size_t)c * 512 + q * 8);
          v8s r = *(const v8s*)(emb16 + (size_t)row * 512 + q * 8);
#pragma unroll
          for (int z = 0; z < 8; ++z) s += bf2f(e[z]) * bf2f(r[z]);
        }
        if (s > L[0]) ins16(L, s);
      }
#pragma unroll
      for (int k = 0; k < 16; ++k) R[k] = L[15 - k];
    }
    float m = R[0] / TEMPV;
    float se = 0.f;
#pragma unroll
    for (int k = 0; k < 16; ++k)
      if (R[k] > -1e29f) se += expf(R[k] / TEMPV - m);
    float lse = m + logf(se);
    atomicAdd(lsum, lse - pterm[row]);
  }
}

__global__ void kout(const float* lsum, const int* nval, float* out) {
  if (threadIdx.x == 0 && blockIdx.x == 0)
    out[0] = lsum[0] / (float)(nval[0] > 0 ? nval[0] : 1);
}

extern "C" void kernel_launch(void* const* d_in, const int* in_sizes, int n_in,
                              void* d_out, int out_size, void* d_ws, size_t ws_size,
                              hipStream_t stream) {
  const float* emb = (const float*)d_in[0];
  const int* lab = (const int*)d_in[1];
  float* out = (float*)d_out;

  char* wsb = (char*)d_ws;
  short* emb16 = (short*)wsb;                       // 8,388,608
  int* hist = (int*)(wsb + 8388608);                // 8,192
  int* cur = (int*)(wsb + 8396800);                 // 8,192
  int* start = (int*)(wsb + 8404992);               // 8,192
  int* rows = (int*)(wsb + 8413184);                // 32,768
  float* pmin = (float*)(wsb + 8445952);            // 32,768
  float* pterm = (float*)(wsb + 8478720);           // 32,768
  int* valid = (int*)(wsb + 8511488);               // 32,768
  float* LsemiW = (float*)(wsb + 8544256);          // 4,194,304
  int* fbcnt = (int*)(wsb + 12738560);              // 4 (+pad 64)
  int* fbrows = (int*)(wsb + 12738624);             // 32,768
  float* fbpart = (float*)(wsb + 12771392);         // 4,194,304 (2048*32*16 f32)
  float* lsum = (float*)(wsb + 16965696);           // 4
  int* nval = (int*)(wsb + 16965700);               // 4

  kconv<<<4096, 256, 0, stream>>>(emb, emb16, hist, cur, lsum, nval, fbcnt);
  khist<<<32, 256, 0, stream>>>(lab, hist);
  kprefsc<<<1, 256, 0, stream>>>(hist, lab, start, cur, rows);
  kpos2<<<2048, 256, 0, stream>>>(emb16, lab, hist, start, rows, pmin, pterm, valid);
  kgemm<<<1024, 256, 0, stream>>>(emb16, lab, pmin, LsemiW);
  kfin<<<32, 256, 0, stream>>>(LsemiW, pterm, valid, lsum, nval, fbcnt, fbrows);
  kfallA<<<256, 256, 0, stream>>>(emb16, lab, fbcnt, fbrows, fbpart);
  kfallB<<<32, 256, 0, stream>>>(emb16, lab, fbcnt, fbrows, fbpart, pterm, lsum);
  kout<<<1, 64, 0, stream>>>(lsum, nval, out);
}

// Round 9
// 219.561 us; speedup vs baseline: 1.6762x; 1.3059x over previous
//
#include <hip/hip_runtime.h>
#include <stdint.h>
#include <stddef.h>

// HardNegativeMiningLoss on MI355X (B=8192, D=512, K=16, TEMP=0.07, labels<2048).
// kconv(bf16+init) -> khist -> kprefsc -> kpos2 -> kgemm (bf16 MFMA; row panel in
// VGPRs; col panel staged in line-coalesced 64B-per-col blocks with both-sides
// XOR swizzle; T3 2-phase dbuf; per-lane register SEMI top-16 mining) -> kfin ->
// kfallA/kfallB -> kout.

#define TEMPV 0.07f
#define NEGV -1e30f

typedef short v8s __attribute__((ext_vector_type(8)));
typedef float v4f __attribute__((ext_vector_type(4)));

__device__ __forceinline__ short f2bf(float f) {
  unsigned u = __float_as_uint(f);
  unsigned r = (u + 0x7fffu + ((u >> 16) & 1u)) >> 16;  // RNE
  return (short)r;
}
__device__ __forceinline__ float bf2f(short s) {
  return __uint_as_float(((unsigned)(unsigned short)s) << 16);
}

__device__ __forceinline__ void gload16(const void* g, void* l) {
  __builtin_amdgcn_global_load_lds((const __attribute__((address_space(1))) unsigned*)g,
                                   (__attribute__((address_space(3))) unsigned*)l, 16, 0, 0);
}

// ---- Batcher odd-even mergesort network for 16 elements (63 comparators) ----
struct SNet { unsigned char a[64]; unsigned char b[64]; int n; };
constexpr SNet mknet16() {
  SNet t{}; t.n = 0;
  for (int p = 1; p < 16; p <<= 1)
    for (int k = p; k >= 1; k >>= 1)
      for (int j = k % p; j + k < 16; j += 2 * k)
        for (int i = 0; i < k; ++i) {
          int x = i + j, y = i + j + k;
          if (y < 16 && (x / (2 * p)) == (y / (2 * p))) {
            t.a[t.n] = (unsigned char)x; t.b[t.n] = (unsigned char)y; ++t.n;
          }
        }
  return t;
}
constexpr SNet NET16 = mknet16();
constexpr int NETN = NET16.n;

__device__ __forceinline__ void sort16d(float (&V)[16]) {
#pragma unroll
  for (int c = 0; c < NETN; ++c) {
    const int x = NET16.a[c], y = NET16.b[c];
    float hi = fmaxf(V[x], V[y]);
    float lo = fminf(V[x], V[y]);
    V[x] = hi; V[y] = lo;
  }
}

// clean a bitonic 16-seq into descending order
__device__ __forceinline__ void clean16d(float (&V)[16]) {
#pragma unroll
  for (int s = 8; s >= 1; s >>= 1) {
#pragma unroll
    for (int i = 0; i < 16; ++i) {
      if ((i & s) == 0) {
        float hi = fmaxf(V[i], V[i + s]);
        float lo = fminf(V[i], V[i + s]);
        V[i] = hi; V[i + s] = lo;
      }
    }
  }
}

// R = top16(R ∪ M), both desc sorted; in-place
__device__ __forceinline__ void mergeld(float (&R)[16], const float (&M)[16]) {
#pragma unroll
  for (int i = 0; i < 8; ++i) {
    float a = fmaxf(M[i], R[15 - i]);
    float b = fmaxf(M[15 - i], R[i]);
    R[i] = a; R[15 - i] = b;
  }
  clean16d(R);
}

// merge my desc-16 with xor-partner lane's desc-16 (both get top-16 of union)
__device__ __forceinline__ void xmerge16(float (&M)[16], int mask) {
#pragma unroll
  for (int i = 0; i < 8; ++i) {
    float pa = __shfl_xor(M[15 - i], mask);
    float pb = __shfl_xor(M[i], mask);
    M[i] = fmaxf(M[i], pa);
    M[15 - i] = fmaxf(M[15 - i], pb);
  }
  clean16d(M);
}

// ascending top-16 insert list (serial guard path only): call when v > L[0]
__device__ __forceinline__ void ins16(float (&L)[16], float v) {
#pragma unroll
  for (int k = 0; k < 15; ++k) {
    float lo = fminf(v, L[k + 1]);
    float hi = fmaxf(v, L[k + 1]);
    L[k] = lo;
    v = hi;
  }
  L[15] = v;
}

// ---------------- small setup kernels ----------------
__global__ void kconv(const float* __restrict__ emb, short* __restrict__ emb16,
                      int* hist, int* cur, float* lsum, int* nval, int* fbcnt) {
  int i = (blockIdx.x * 256 + threadIdx.x) * 4;
  float4 v = *(const float4*)(emb + i);
  short4 s;
  s.x = f2bf(v.x); s.y = f2bf(v.y); s.z = f2bf(v.z); s.w = f2bf(v.w);
  *(short4*)(emb16 + i) = s;
  if (blockIdx.x < 8) {
    int j = blockIdx.x * 256 + threadIdx.x;
    hist[j] = 0; cur[j] = 0;
    if (j == 0) { *lsum = 0.f; *nval = 0; *fbcnt = 0; }
  }
}

__global__ void khist(const int* __restrict__ lab, int* hist) {
  int i = blockIdx.x * 256 + threadIdx.x;
  if (i < 8192) atomicAdd(&hist[lab[i]], 1);
}

__global__ __launch_bounds__(256) void kprefsc(const int* __restrict__ hist,
                                               const int* __restrict__ lab,
                                               int* __restrict__ start,
                                               int* cur, int* __restrict__ rows) {
  __shared__ int part[256];
  int t = threadIdx.x;
  int v[8], loc[8], s = 0;
#pragma unroll
  for (int k = 0; k < 8; ++k) v[k] = hist[t * 8 + k];
#pragma unroll
  for (int k = 0; k < 8; ++k) { loc[k] = s; s += v[k]; }
  part[t] = s;
  __syncthreads();
  for (int off = 1; off < 256; off <<= 1) {
    int x = (t >= off) ? part[t - off] : 0;
    __syncthreads();
    part[t] += x;
    __syncthreads();
  }
  int base = (t > 0) ? part[t - 1] : 0;
#pragma unroll
  for (int k = 0; k < 8; ++k) start[t * 8 + k] = base + loc[k];
  __syncthreads();
  for (int i = t; i < 8192; i += 256) {
    int li = lab[i];
    int p = atomicAdd(&cur[li], 1);
    rows[start[li] + p] = i;
  }
}

__global__ __launch_bounds__(256) void kpos2(const short* __restrict__ emb16,
                                             const int* __restrict__ lab,
                                             const int* __restrict__ hist,
                                             const int* __restrict__ start,
                                             const int* __restrict__ rows,
                                             float* __restrict__ pmin,
                                             float* __restrict__ pterm,
                                             int* __restrict__ valid) {
  int t = threadIdx.x;
  int wv = t >> 6, lane = t & 63;
  int i = blockIdx.x * 4 + wv;
  int li = lab[i];
  int s0 = start[li], c = hist[li];
  float ei[8];
  v8s e = *(const v8s*)(emb16 + (size_t)i * 512 + lane * 8);
#pragma unroll
  for (int k = 0; k < 8; ++k) ei[k] = bf2f(e[k]);
  float smin = 1e30f, ssum = 0.f;
  for (int k = 0; k < c; ++k) {
    int j = rows[s0 + k];
    if (j == i) continue;
    v8s f = *(const v8s*)(emb16 + (size_t)j * 512 + lane * 8);
    float s = 0.f;
#pragma unroll
    for (int q = 0; q < 8; ++q) s += ei[q] * bf2f(f[q]);
#pragma unroll
    for (int off = 32; off; off >>= 1) s += __shfl_xor(s, off);
    smin = fminf(smin, s);
    ssum += s;
  }
  if (lane == 0) {
    int pc = c - 1, nc = 8192 - c;
    pmin[i] = smin;                                   // +1e30 when no positives
    pterm[i] = ssum / (float)(pc > 0 ? pc : 1) / TEMPV;
    valid[i] = (pc > 0 && nc > 0) ? 1 : 0;
  }
}

// ---------------- main mining GEMM (line-coalesced staging) ----------------
// Grid 1024 = 128 row-blocks(BM=64) x 8 col-blocks (1024 cols; cb=bid&7 -> XCD).
// Row panel: in VGPRs — each wave owns 16 rows (row = wv*16 + l15), b-frag regs
// breg[16] (64 VGPR), loaded once, 16 full 64B lines per load instr.
// Col panel: Cg[2][256col][32k] bf16 dbuf (2x16KB). Stage instr reads 16 cols x
// 64B CONTIGUOUS (fully-used L2 lines — the round-8 fix: no more 16B/64B-line
// gathers). LDS dest is forced-linear -> col-major 64B blocks; bank conflicts
// fixed rule-21 style: source pre-swizzle chunk^=(col&3) + same XOR on ds_read.
// 64 stages = 4 col-tiles(256) x 16 K-steps(32); T3 order per stage:
// STAGE(next) -> ds_read+MFMA x16 -> [mine at kst==15] -> vmcnt(0) -> s_barrier.
// acc[mi][r] = sim[row=wv*16+l15][ct*256 + mi*16 + l4*4 + r].
__global__ __launch_bounds__(256, 2) void kgemm(const short* __restrict__ emb16,
                                                const int* __restrict__ lab,
                                                const float* __restrict__ pminA,
                                                float* __restrict__ Lsemi) {
  __shared__ __align__(16) short Cg[2][256][32];  // 32KB

  int t = threadIdx.x;
  int bid = blockIdx.x;
  int rb = bid >> 3, cb = bid & 7;
  int rowbase = rb * 64;
  int colblock = cb * 1024;

  int wv = t >> 6, l = t & 63;
  int l15 = l & 15, l4 = l >> 4;

  int myrow = rowbase + wv * 16 + l15;
  int rlab = lab[myrow];
  float pm = pminA[myrow];

  // row-panel b-fragments in registers (64 VGPR), coalesced 64B-per-row loads
  v8s breg[16];
#pragma unroll
  for (int kst = 0; kst < 16; ++kst)
    breg[kst] = *(const v8s*)(emb16 + (size_t)myrow * 512 + kst * 32 + l4 * 8);

  float RS[16];
#pragma unroll
  for (int k = 0; k < 16; ++k) RS[k] = NEGV;

  v4f acc[16];
#pragma unroll
  for (int mi = 0; mi < 16; ++mi) acc[mi] = (v4f)0.f;

  // stage s=0 into buf 0: cols [colblock, +256), K-window [0,32)
#pragma unroll
  for (int q = 0; q < 4; ++q) {
    int e = q * 256 + t;
    int col = e >> 2, ch = e & 3;
    gload16(emb16 + ((size_t)(colblock + col) * 512 + ((ch ^ (col & 3)) * 8)),
            &Cg[0][col][ch * 8]);
  }
  asm volatile("s_waitcnt vmcnt(0)" ::: "memory");
  __builtin_amdgcn_s_barrier();

  const int apos = (l4 ^ (l15 & 3)) * 8;  // swizzled read chunk position

  for (int s = 0; s < 64; ++s) {
    const int ct = s >> 4, kst = s & 15;
    const int cur = s & 1;
    // (1) issue next stage's loads (T3: stage-issue first; other buffer)
    if (s + 1 < 64) {
      const int nct = (s + 1) >> 4, nkst = (s + 1) & 15;
      const int nb = (s + 1) & 1;
#pragma unroll
      for (int q = 0; q < 4; ++q) {
        int e = q * 256 + t;
        int col = e >> 2, ch = e & 3;
        gload16(emb16 + ((size_t)(colblock + nct * 256 + col) * 512 + nkst * 32 +
                         ((ch ^ (col & 3)) * 8)),
                &Cg[nb][col][ch * 8]);
      }
    }
    // (2) ds_read + MFMA, 16 fragments (reads are conflict-free via swizzle)
#pragma unroll
    for (int mi = 0; mi < 16; ++mi) {
      v8s a = *(const v8s*)&Cg[cur][mi * 16 + l15][apos];
      acc[mi] = __builtin_amdgcn_mfma_f32_16x16x32_bf16(a, breg[kst], acc[mi], 0, 0, 0);
    }
    // (3) mine at col-tile end (full-K sums ready); extra cover for the stage
    if (kst == 15) {
      const int colstart = colblock + ct * 256;
#pragma unroll
      for (int c = 0; c < 4; ++c) {
        int lc[4][4];
#pragma unroll
        for (int mm = 0; mm < 4; ++mm) {
          int4 q = *(const int4*)&lab[colstart + (c * 4 + mm) * 16 + l4 * 4];
          lc[mm][0] = q.x; lc[mm][1] = q.y; lc[mm][2] = q.z; lc[mm][3] = q.w;
        }
        float S[16];
#pragma unroll
        for (int j = 0; j < 16; ++j) {
          const int mi = c * 4 + (j >> 2), r = j & 3;
          float v = acc[mi][r];
          bool keep = (lc[j >> 2][r] != rlab) && (v < pm);
          S[j] = keep ? v : NEGV;
        }
        sort16d(S);
        mergeld(RS, S);
      }
#pragma unroll
      for (int mi = 0; mi < 16; ++mi) acc[mi] = (v4f)0.f;
    }
    // (4) drain in-flight stage (covered by MFMA/mining), (5) barrier
    asm volatile("s_waitcnt vmcnt(0)" ::: "memory");
    __builtin_amdgcn_s_barrier();
  }

  // cross-lane merge (4 l4-groups share each row); rows are wave-exclusive
  xmerge16(RS, 16);
  xmerge16(RS, 32);
  if (l4 == 0) {
    size_t o = ((size_t)cb * 8192 + myrow) * 16;
#pragma unroll
    for (int k = 0; k < 4; ++k)
      *(float4*)&Lsemi[o + k * 4] =
          make_float4(RS[k * 4], RS[k * 4 + 1], RS[k * 4 + 2], RS[k * 4 + 3]);
  }
}

// merge 8 col-block semi partials, masked LSE, detect fallback rows, reduce
__global__ __launch_bounds__(256) void kfin(const float* __restrict__ Lsemi,
                                            const float* __restrict__ pterm,
                                            const int* __restrict__ valid,
                                            float* lsum, int* nval,
                                            int* fbcnt, int* fbrows) {
  int i = blockIdx.x * 256 + threadIdx.x;
  float S[16], M[16];
#pragma unroll
  for (int k = 0; k < 16; ++k) S[k] = Lsemi[(size_t)i * 16 + k];
  for (int c = 1; c < 8; ++c) {
    size_t o = ((size_t)c * 8192 + i) * 16;
#pragma unroll
    for (int k = 0; k < 16; ++k) M[k] = Lsemi[o + k];
    mergeld(S, M);
  }
  int vd = valid[i];
  bool hs = S[0] > -1e29f;
  float li = 0.f;
  if (vd && !hs) {
    int idx = atomicAdd(fbcnt, 1);
    fbrows[idx] = i;          // loss added by kfallB
  } else if (vd) {
    float m = S[0] / TEMPV;
    float se = 0.f;
#pragma unroll
    for (int k = 0; k < 16; ++k)
      if (S[k] > -1e29f) se += expf(S[k] / TEMPV - m);
    li = m + logf(se) - pterm[i];
  }
#pragma unroll
  for (int off = 32; off; off >>= 1) {
    li += __shfl_xor(li, off);
    vd += __shfl_xor(vd, off);
  }
  __shared__ float rsd[4];
  __shared__ int rid[4];
  int wv = threadIdx.x >> 6;
  if ((threadIdx.x & 63) == 0) { rsd[wv] = li; rid[wv] = vd; }
  __syncthreads();
  if (threadIdx.x == 0) {
    atomicAdd(lsum, rsd[0] + rsd[1] + rsd[2] + rsd[3]);
    atomicAdd(nval, rid[0] + rid[1] + rid[2] + rid[3]);
  }
}

// Parallel fallback phase A: unit u = (f, j) -> row fbrows[f], candidates
// [j*256, j*256+256). One candidate per thread; block-top-16 via wave butterfly.
__global__ __launch_bounds__(256) void kfallA(const short* __restrict__ emb16,
                                              const int* __restrict__ lab,
                                              const int* __restrict__ fbcnt,
                                              const int* __restrict__ fbrows,
                                              float* __restrict__ fbpart) {
  int nfb = *fbcnt;
  if (nfb > 2048) nfb = 2048;
  int nunits = nfb * 32;
  __shared__ short remb[512];
  __shared__ float sims[256];
  int t = threadIdx.x;
  for (int u = blockIdx.x; u < nunits; u += gridDim.x) {
    int f = u >> 5, j = u & 31;
    int row = fbrows[f];
    int rl = lab[row];
    __syncthreads();  // prior iteration's reads of remb/sims complete
    if (t < 64) *(v8s*)&remb[t * 8] = *(const v8s*)(emb16 + (size_t)row * 512 + t * 8);
    __syncthreads();
    int c = j * 256 + t;
    float s = 0.f;
#pragma unroll 8
    for (int q = 0; q < 64; ++q) {
      v8s e = *(const v8s*)(emb16 + (size_t)c * 512 + q * 8);
      v8s r = *(const v8s*)&remb[q * 8];
#pragma unroll
      for (int z = 0; z < 8; ++z) s += bf2f(e[z]) * bf2f(r[z]);
    }
    sims[t] = (lab[c] != rl) ? s : NEGV;
    __syncthreads();
    if (t < 64) {
      float M[16];
#pragma unroll
      for (int k = 0; k < 16; ++k) M[k] = NEGV;
      M[0] = sims[t]; M[1] = sims[64 + t]; M[2] = sims[128 + t]; M[3] = sims[192 + t];
      sort16d(M);
      xmerge16(M, 1); xmerge16(M, 2); xmerge16(M, 4);
      xmerge16(M, 8); xmerge16(M, 16); xmerge16(M, 32);
      if (t == 0) {
#pragma unroll
        for (int k = 0; k < 16; ++k) fbpart[(size_t)(f * 32 + j) * 16 + k] = M[k];
      }
    }
  }
}

// Parallel fallback phase B: one thread per fallback row merges 32 partials,
// computes LSE, adds loss. Serial exact path only for f >= 2048 (never expected).
__global__ __launch_bounds__(256) void kfallB(const short* __restrict__ emb16,
                                              const int* __restrict__ lab,
                                              const int* __restrict__ fbcnt,
                                              const int* __restrict__ fbrows,
                                              const float* __restrict__ fbpart,
                                              const float* __restrict__ pterm,
                                              float* lsum) {
  int nfb = *fbcnt;
  int gid = blockIdx.x * 256 + threadIdx.x;
  for (int f = gid; f < nfb; f += gridDim.x * 256) {
    int row = fbrows[f];
    float R[16];
    if (f < 2048) {
#pragma unroll
      for (int k = 0; k < 16; ++k) R[k] = fbpart[(size_t)(f * 32) * 16 + k];
      for (int j = 1; j < 32; ++j) {
        float M[16];
#pragma unroll
        for (int k = 0; k < 16; ++k) M[k] = fbpart[(size_t)(f * 32 + j) * 16 + k];
        mergeld(R, M);
      }
    } else {
      int rl = lab[row];
      float L[16];
#pragma unroll
      for (int k = 0; k < 16; ++k) L[k] = NEGV;
      for (int c = 0; c < 8192; ++c) {
        if (lab[c] == rl) continue;
        float s = 0.f;
        for (int q = 0; q < 64; ++q) {
          v8s e = *(const v8s*)(emb16 + (size_t)c * 512 + q * 8);
          v8s r = *(const v8s*)(emb16 + (size_t)row * 512 + q * 8);
#pragma unroll
          for (int z = 0; z < 8; ++z) s += bf2f(e[z]) * bf2f(r[z]);
        }
        if (s > L[0]) ins16(L, s);
      }
#pragma unroll
      for (int k = 0; k < 16; ++k) R[k] = L[15 - k];
    }
    float m = R[0] / TEMPV;
    float se = 0.f;
#pragma unroll
    for (int k = 0; k < 16; ++k)
      if (R[k] > -1e29f) se += expf(R[k] / TEMPV - m);
    float lse = m + logf(se);
    atomicAdd(lsum, lse - pterm[row]);
  }
}

__global__ void kout(const float* lsum, const int* nval, float* out) {
  if (threadIdx.x == 0 && blockIdx.x == 0)
    out[0] = lsum[0] / (float)(nval[0] > 0 ? nval[0] : 1);
}

extern "C" void kernel_launch(void* const* d_in, const int* in_sizes, int n_in,
                              void* d_out, int out_size, void* d_ws, size_t ws_size,
                              hipStream_t stream) {
  const float* emb = (const float*)d_in[0];
  const int* lab = (const int*)d_in[1];
  float* out = (float*)d_out;

  char* wsb = (char*)d_ws;
  short* emb16 = (short*)wsb;                       // 8,388,608
  int* hist = (int*)(wsb + 8388608);                // 8,192
  int* cur = (int*)(wsb + 8396800);                 // 8,192
  int* start = (int*)(wsb + 8404992);               // 8,192
  int* rows = (int*)(wsb + 8413184);                // 32,768
  float* pmin = (float*)(wsb + 8445952);            // 32,768
  float* pterm = (float*)(wsb + 8478720);           // 32,768
  int* valid = (int*)(wsb + 8511488);               // 32,768
  float* LsemiW = (float*)(wsb + 8544256);          // 4,194,304
  int* fbcnt = (int*)(wsb + 12738560);              // 4 (+pad 64)
  int* fbrows = (int*)(wsb + 12738624);             // 32,768
  float* fbpart = (float*)(wsb + 12771392);         // 4,194,304
  float* lsum = (float*)(wsb + 16965696);           // 4
  int* nval = (int*)(wsb + 16965700);               // 4

  kconv<<<4096, 256, 0, stream>>>(emb, emb16, hist, cur, lsum, nval, fbcnt);
  khist<<<32, 256, 0, stream>>>(lab, hist);
  kprefsc<<<1, 256, 0, stream>>>(hist, lab, start, cur, rows);
  kpos2<<<2048, 256, 0, stream>>>(emb16, lab, hist, start, rows, pmin, pterm, valid);
  kgemm<<<1024, 256, 0, stream>>>(emb16, lab, pmin, LsemiW);
  kfin<<<32, 256, 0, stream>>>(LsemiW, pterm, valid, lsum, nval, fbcnt, fbrows);
  kfallA<<<256, 256, 0, stream>>>(emb16, lab, fbcnt, fbrows, fbpart);
  kfallB<<<32, 256, 0, stream>>>(emb16, lab, fbcnt, fbrows, fbpart, pterm, lsum);
  kout<<<1, 64, 0, stream>>>(lsum, nval, out);
}